// Round 14
// baseline (171.890 us; speedup 1.0000x reference)
//
#include <hip/hip_runtime.h>

// VQ nearest-neighbor: codes (64,4096,64) fp32, codebook (1024,64) fp32.
// Outputs flat in d_out: quant_codes [M*64] f32, then quant_id [M] (as f32).
//
// Round 14 = round 13 (verified, 160.6us) with vq_approx restructured for
// occupancy: 32 queries/wave (live set ~96 regs < 128 => 4 waves/SIMD) and
// block-level LDS sharing of B fragments (4 waves/block, double-buffered,
// one barrier/tile, issue-early/write-late staging). Per-score math is
// BITWISE IDENTICAL to r13 (same 6-MFMA chain, tracking, butterfly, THR).
// csq / cb_convert / vq_fixup / vq_gather are r13-VERBATIM.

#define NUM_NT 1024
#define DIM 64
#define M_TOTAL (64 * 4096)
#define NTILES 64
#define THR 1.0e-3f            // verified r13 (5x margin over ~2e-4 bound)

typedef __attribute__((ext_vector_type(8))) short short8;   // 8 bf16
typedef __attribute__((ext_vector_type(4))) float f32x4;

static __device__ __forceinline__ unsigned short f2bf_rne(float f) {
    unsigned u = __builtin_bit_cast(unsigned, f);
    u += 0x7FFFu + ((u >> 16) & 1u);          // round-to-nearest-even
    return (unsigned short)(u >> 16);
}
static __device__ __forceinline__ float bf2f(unsigned short h) {
    unsigned u = ((unsigned)h) << 16;
    return __builtin_bit_cast(float, u);
}

// ---------------------------------------------------------------------------
// Phase 0a: hcsq[k] = 0.5*||c_k||^2; block 0 zeroes the worklist counter.
// (r13-verbatim)
// ---------------------------------------------------------------------------
__global__ __launch_bounds__(64) void csq_kernel(const float* __restrict__ cb,
                                                 float* __restrict__ hcsq,
                                                 int* __restrict__ counter) {
    int k = blockIdx.x, d = threadIdx.x;
    if (k == 0 && d == 0) *counter = 0;
    float v = cb[k * DIM + d];
    float s = v * v;
    #pragma unroll
    for (int off = 32; off > 0; off >>= 1) s += __shfl_down(s, off);
    if (d == 0) hcsq[k] = 0.5f * s;
}

// ---------------------------------------------------------------------------
// Phase 0b: codebook -> bf16 hi/lo fragments in MFMA B-layout. (r13-verbatim)
// ---------------------------------------------------------------------------
__global__ __launch_bounds__(256) void cb_convert(const float* __restrict__ cb,
                                                  short8* __restrict__ bh,
                                                  short8* __restrict__ bl) {
    int gtid = blockIdx.x * 256 + threadIdx.x;   // 8192 = 128 frags x 64 lanes
    int f = gtid >> 6;
    int lane = gtid & 63;
    int t = f >> 1, kk = f & 1;
    int n = t * 16 + (lane & 15);
    int k0 = kk * 32 + 8 * (lane >> 4);
    const float* p = cb + n * DIM + k0;
    short8 h, l;
    #pragma unroll
    for (int e = 0; e < 8; ++e) {
        float v = p[e];
        unsigned short hb = f2bf_rne(v);
        h[e] = (short)hb;
        l[e] = (short)f2bf_rne(v - bf2f(hb));
    }
    bh[f * 64 + lane] = h;
    bl[f * 64 + lane] = l;
}

// ---------------------------------------------------------------------------
// Phase 1: approx scores via 3-pass bf16 MFMA.
// 32 queries/wave (2 A-sets); block = 4 waves = 128 queries.
// B fragments staged per-BLOCK in double-buffered LDS (all 4 waves read the
// same B). One barrier per tile; staging load issued early, ds_write late.
// Tracking / butterfly / marker: r13-VERBATIM semantics.
// ---------------------------------------------------------------------------
__global__ __launch_bounds__(256) void vq_approx(const float* __restrict__ codes,
                                                 const short8* __restrict__ bh,
                                                 const short8* __restrict__ bl,
                                                 const float* __restrict__ hcsq,
                                                 float* __restrict__ out_ids,
                                                 int* __restrict__ worklist,
                                                 int* __restrict__ counter) {
    __shared__ short8 lb[2][2][2][64];   // [buf][arr: 0=hi 1=lo][kk][lane] 8KB
    const int tid  = threadIdx.x;
    const int lane = tid & 63;
    const int wv   = tid >> 6;
    const int qb   = (blockIdx.x * 4 + wv) * 32;   // 32 queries per wave
    const int c16  = lane & 15;
    const int kg   = lane >> 4;

    // Staging role of this thread: one 16B fragment chunk per tile.
    const int sarr = (tid >> 7) & 1;               // 0: bh, 1: bl
    const int skk  = (tid >> 6) & 1;               // fragment kk
    const short8* __restrict__ sptr = sarr ? bl : bh;

    // Load + split 2 A-sets (negated query rows), bf16 hi/lo (r13 pattern).
    short8 ah[2][2], al[2][2];
    #pragma unroll
    for (int s = 0; s < 2; ++s) {
        const float* xr = codes + (size_t)(qb + s * 16 + c16) * DIM + kg * 8;
        #pragma unroll
        for (int e = 0; e < 8; ++e) {
            float v = -xr[e];
            unsigned short hb = f2bf_rne(v);
            ah[s][0][e] = (short)hb;
            al[s][0][e] = (short)f2bf_rne(v - bf2f(hb));
            float w = -xr[32 + e];
            unsigned short hw = f2bf_rne(w);
            ah[s][1][e] = (short)hw;
            al[s][1][e] = (short)f2bf_rne(w - bf2f(hw));
        }
    }

    float d1[8], d2[8];
    int   tb[8];
    #pragma unroll
    for (int r = 0; r < 8; ++r) { d1[r] = 3.4e38f; d2[r] = 3.4e38f; tb[r] = 0; }

    // Stage tile 0 into buffer 0.
    lb[0][sarr][skk][lane] = sptr[(0 * 2 + skk) * 64 + lane];
    __syncthreads();

    for (int t = 0; t < NTILES; ++t) {
        const int cur = t & 1;
        // Issue next tile's global load EARLY (latency hides under MFMA).
        short8 stg;
        if (t + 1 < NTILES)
            stg = sptr[((t + 1) * 2 + skk) * 64 + lane];

        // Read this tile's B fragments from LDS.
        short8 vh0 = lb[cur][0][0][lane];
        short8 vh1 = lb[cur][0][1][lane];
        short8 vl0 = lb[cur][1][0][lane];
        short8 vl1 = lb[cur][1][1][lane];
        float hc = hcsq[t * 16 + c16];
        f32x4 hcv = {hc, hc, hc, hc};
        #pragma unroll
        for (int s = 0; s < 2; ++s) {
            f32x4 acc = hcv;   // score = 0.5*||c||^2 - x.c  (r13-identical chain)
            acc = __builtin_amdgcn_mfma_f32_16x16x32_bf16(ah[s][0], vh0, acc, 0, 0, 0);
            acc = __builtin_amdgcn_mfma_f32_16x16x32_bf16(al[s][0], vh0, acc, 0, 0, 0);
            acc = __builtin_amdgcn_mfma_f32_16x16x32_bf16(ah[s][0], vl0, acc, 0, 0, 0);
            acc = __builtin_amdgcn_mfma_f32_16x16x32_bf16(ah[s][1], vh1, acc, 0, 0, 0);
            acc = __builtin_amdgcn_mfma_f32_16x16x32_bf16(al[s][1], vh1, acc, 0, 0, 0);
            acc = __builtin_amdgcn_mfma_f32_16x16x32_bf16(ah[s][1], vl1, acc, 0, 0, 0);
            #pragma unroll
            for (int rr = 0; rr < 4; ++rr) {
                float d = acc[rr];
                int r = s * 4 + rr;
                bool take = d < d1[r];                    // strict: first min wins
                d2[r] = __builtin_amdgcn_fmed3f(d1[r], d2[r], d);  // min(d2,max(d1,d))
                d1[r] = fminf(d1[r], d);
                tb[r] = take ? t : tb[r];
            }
        }

        // Write next tile's fragment to the other buffer, then sync.
        if (t + 1 < NTILES)
            lb[cur ^ 1][sarr][skk][lane] = stg;
        __syncthreads();
    }

    // Cross-lane argmin within each 16-lane group (r13-verbatim butterfly).
    #pragma unroll
    for (int r = 0; r < 8; ++r) {
        float dd1 = d1[r], dd2 = d2[r];
        int idv = tb[r] * 16 + c16;
        #pragma unroll
        for (int m = 1; m < 16; m <<= 1) {
            float d_o  = __shfl_xor(dd1, m, 64);
            int   i_o  = __shfl_xor(idv, m, 64);
            float d2_o = __shfl_xor(dd2, m, 64);
            float nd2 = fminf(fminf(dd2, d2_o), fmaxf(dd1, d_o));
            bool take = (d_o < dd1) || (d_o == dd1 && i_o < idv);
            dd1 = take ? d_o : dd1;
            idv = take ? i_o : idv;
            dd2 = nd2;
        }
        if (c16 == 0) {
            int q = qb + (r >> 2) * 16 + kg * 4 + (r & 3);
            out_ids[q] = (float)idv;
            if (dd2 - dd1 < THR) {                       // near-tie -> rescan
                int slot = atomicAdd(counter, 1);
                worklist[slot] = q;
            }
        }
    }
}

// ---------------------------------------------------------------------------
// Fixup: one wave per worklist entry (grid-stride). Exact fp32 rescan,
// bitwise-identical math to the validated round-1 kernel. (r13-verbatim)
// ---------------------------------------------------------------------------
__global__ __launch_bounds__(256) void vq_fixup(const float* __restrict__ codes,
                                                const float* __restrict__ cb,
                                                const float* __restrict__ hcsq,
                                                const int* __restrict__ worklist,
                                                const int* __restrict__ counter,
                                                float* __restrict__ out_ids) {
    const int lane = threadIdx.x & 63;
    const int wid  = blockIdx.x * 4 + (threadIdx.x >> 6);
    const int nw   = gridDim.x * 4;
    const int cnt  = *counter;

    for (int w = wid; w < cnt; w += nw) {
        const int q = worklist[w];
        float x[64];
        const float4* xp = reinterpret_cast<const float4*>(codes + (size_t)q * DIM);
        #pragma unroll
        for (int i = 0; i < 16; ++i) {
            float4 v = xp[i];
            x[4*i+0] = v.x; x[4*i+1] = v.y; x[4*i+2] = v.z; x[4*i+3] = v.w;
        }
        float best = 3.4e38f; int bid = 0;
        for (int jj = 0; jj < 16; ++jj) {
            int k = jj * 64 + lane;
            const float4* cp = reinterpret_cast<const float4*>(cb + (size_t)k * DIM);
            float acc = hcsq[k];
            #pragma unroll
            for (int i = 0; i < 16; ++i) {
                float4 c = cp[i];
                acc = fmaf(-x[4*i+0], c.x, acc);
                acc = fmaf(-x[4*i+1], c.y, acc);
                acc = fmaf(-x[4*i+2], c.z, acc);
                acc = fmaf(-x[4*i+3], c.w, acc);
            }
            if (acc < best) { best = acc; bid = k; }   // strict: lowest k wins
        }
        #pragma unroll
        for (int m = 1; m < 64; m <<= 1) {
            float d_o = __shfl_xor(best, m, 64);
            int   i_o = __shfl_xor(bid, m, 64);
            bool take = (d_o < best) || (d_o == best && i_o < bid);
            best = take ? d_o : best;
            bid  = take ? i_o : bid;
        }
        int id = __shfl(bid, 0, 64);
        if (lane == 0) out_ids[q] = (float)id;
    }
}

// ---------------------------------------------------------------------------
// Gather: scratch-free streaming gather/store of codebook rows. (r13-verbatim)
// ---------------------------------------------------------------------------
__global__ __launch_bounds__(256) void vq_gather(const float* __restrict__ cb,
                                                 const float* __restrict__ out_ids,
                                                 float4* __restrict__ out_codes4) {
    const int base = blockIdx.x * 256 + threadIdx.x;
    const int STRIDE = 4096 * 256;                 // total threads
    const float4* cb4 = reinterpret_cast<const float4*>(cb);

    float fids[4];
    #pragma unroll
    for (int u = 0; u < 4; ++u)
        fids[u] = out_ids[(base + u * STRIDE) >> 4];

    #pragma unroll
    for (int u = 0; u < 4; ++u) {
        int i = base + u * STRIDE;
        int id = (int)fids[u];
        out_codes4[i] = cb4[id * 16 + (i & 15)];
    }
}

// ---------------------------------------------------------------------------
extern "C" void kernel_launch(void* const* d_in, const int* in_sizes, int n_in,
                              void* d_out, int out_size, void* d_ws, size_t ws_size,
                              hipStream_t stream) {
    const float* codes = (const float*)d_in[0];
    const float* cb    = (const float*)d_in[1];
    float* out         = (float*)d_out;

    float* out_codes = out;
    float* out_ids   = out + (size_t)M_TOTAL * DIM;

    // ws: [0,4K) hcsq | [4K,132K) bh | [132K,260K) bl | [264K) counter |
    //     [268K, 268K+1M) worklist
    float*  hcsq     = (float*)d_ws;
    short8* bh       = (short8*)((char*)d_ws + 4096);
    short8* bl       = (short8*)((char*)d_ws + 4096 + 128 * 1024);
    int*    counter  = (int*)((char*)d_ws + 264 * 1024);
    int*    worklist = (int*)((char*)d_ws + 268 * 1024);

    csq_kernel<<<NUM_NT, 64, 0, stream>>>(cb, hcsq, counter);
    cb_convert<<<32, 256, 0, stream>>>(cb, bh, bl);
    vq_approx<<<M_TOTAL / 128, 256, 0, stream>>>(codes, bh, bl, hcsq,
                                                 out_ids, worklist, counter);
    vq_fixup<<<512, 256, 0, stream>>>(codes, cb, hcsq, worklist, counter, out_ids);
    vq_gather<<<4096, 256, 0, stream>>>(cb, out_ids, (float4*)out_codes);
}

// Round 15
// 154.467 us; speedup vs baseline: 1.1128x; 1.1128x over previous
//
#include <hip/hip_runtime.h>

// VQ nearest-neighbor: codes (64,4096,64) fp32, codebook (1024,64) fp32.
// Outputs flat in d_out: quant_codes [M*64] f32, then quant_id [M] (as f32).
//
// Round 15 = round 13's verified approx (127us, best measured) with:
//   (a) fused code-row gather/store in the epilogue (vq_gather DELETED;
//       its ~19us now hides under approx's compute)
//   (b) acc init = 0.5f constant (codebook rows are L2-normalized =>
//       0.5*||c||^2 = 0.5 +- ~5e-7; error negligible vs THR=1e-3 margin)
// vq_fixup now also rewrites the code row for flagged queries.
// csq / cb_convert r13-VERBATIM. fixup math r1-verbatim.

#define NUM_NT 1024
#define DIM 64
#define M_TOTAL (64 * 4096)
#define NTILES 64
#define THR 1.0e-3f            // verified r13 (5x margin over ~2e-4 bound)

typedef __attribute__((ext_vector_type(8))) short short8;   // 8 bf16
typedef __attribute__((ext_vector_type(4))) float f32x4;

static __device__ __forceinline__ unsigned short f2bf_rne(float f) {
    unsigned u = __builtin_bit_cast(unsigned, f);
    u += 0x7FFFu + ((u >> 16) & 1u);          // round-to-nearest-even
    return (unsigned short)(u >> 16);
}
static __device__ __forceinline__ float bf2f(unsigned short h) {
    unsigned u = ((unsigned)h) << 16;
    return __builtin_bit_cast(float, u);
}

// ---------------------------------------------------------------------------
// Phase 0a: hcsq[k] = 0.5*||c_k||^2 (fixup's r1-exact math needs it);
// block 0 zeroes the worklist counter. (r13-verbatim)
// ---------------------------------------------------------------------------
__global__ __launch_bounds__(64) void csq_kernel(const float* __restrict__ cb,
                                                 float* __restrict__ hcsq,
                                                 int* __restrict__ counter) {
    int k = blockIdx.x, d = threadIdx.x;
    if (k == 0 && d == 0) *counter = 0;
    float v = cb[k * DIM + d];
    float s = v * v;
    #pragma unroll
    for (int off = 32; off > 0; off >>= 1) s += __shfl_down(s, off);
    if (d == 0) hcsq[k] = 0.5f * s;
}

// ---------------------------------------------------------------------------
// Phase 0b: codebook -> bf16 hi/lo fragments in MFMA B-layout. (r13-verbatim)
// ---------------------------------------------------------------------------
__global__ __launch_bounds__(256) void cb_convert(const float* __restrict__ cb,
                                                  short8* __restrict__ bh,
                                                  short8* __restrict__ bl) {
    int gtid = blockIdx.x * 256 + threadIdx.x;   // 8192 = 128 frags x 64 lanes
    int f = gtid >> 6;
    int lane = gtid & 63;
    int t = f >> 1, kk = f & 1;
    int n = t * 16 + (lane & 15);
    int k0 = kk * 32 + 8 * (lane >> 4);
    const float* p = cb + n * DIM + k0;
    short8 h, l;
    #pragma unroll
    for (int e = 0; e < 8; ++e) {
        float v = p[e];
        unsigned short hb = f2bf_rne(v);
        h[e] = (short)hb;
        l[e] = (short)f2bf_rne(v - bf2f(hb));
    }
    bh[f * 64 + lane] = h;
    bl[f * 64 + lane] = l;
}

// ---------------------------------------------------------------------------
// Phase 1: approx scores via 3-pass bf16 MFMA, 64 queries/wave, register
// double-buffer B prefetch, fmed3 second-best (r13-verbatim structure).
// Changes: acc init = 0.5f const (no hcsq in loop); epilogue gathers the
// winning codebook row (id uniform across the 16-lane group after the
// butterfly) and writes codes + ids; flagged q -> worklist.
// ---------------------------------------------------------------------------
__global__ __launch_bounds__(256, 2) void vq_approx(const float* __restrict__ codes,
                                                    const short8* __restrict__ bh,
                                                    const short8* __restrict__ bl,
                                                    const float* __restrict__ cb,
                                                    float* __restrict__ out_codes,
                                                    float* __restrict__ out_ids,
                                                    int* __restrict__ worklist,
                                                    int* __restrict__ counter) {
    const int lane = threadIdx.x & 63;
    const int wv   = threadIdx.x >> 6;
    const int qb   = (blockIdx.x * 4 + wv) * 64;   // 64 queries per wave
    const int c16  = lane & 15;
    const int kg   = lane >> 4;

    short8 ah[4][2], al[4][2];
    #pragma unroll
    for (int s = 0; s < 4; ++s) {
        const float* xr = codes + (size_t)(qb + s * 16 + c16) * DIM + kg * 8;
        #pragma unroll
        for (int e = 0; e < 8; ++e) {
            float v = -xr[e];
            unsigned short hb = f2bf_rne(v);
            ah[s][0][e] = (short)hb;
            al[s][0][e] = (short)f2bf_rne(v - bf2f(hb));
            float w = -xr[32 + e];
            unsigned short hw = f2bf_rne(w);
            ah[s][1][e] = (short)hw;
            al[s][1][e] = (short)f2bf_rne(w - bf2f(hw));
        }
    }

    float d1[16], d2[16];
    int   tb[16];
    #pragma unroll
    for (int r = 0; r < 16; ++r) { d1[r] = 3.4e38f; d2[r] = 3.4e38f; tb[r] = 0; }

    short8 pvh0 = bh[0 * 64 + lane];
    short8 pvl0 = bl[0 * 64 + lane];
    short8 pvh1 = bh[1 * 64 + lane];
    short8 pvl1 = bl[1 * 64 + lane];

    for (int t = 0; t < NTILES; ++t) {
        short8 vh0 = pvh0, vl0 = pvl0, vh1 = pvh1, vl1 = pvl1;
        if (t + 1 < NTILES) {            // issue next-tile loads before MFMA
            pvh0 = bh[(t * 2 + 2) * 64 + lane];
            pvl0 = bl[(t * 2 + 2) * 64 + lane];
            pvh1 = bh[(t * 2 + 3) * 64 + lane];
            pvl1 = bl[(t * 2 + 3) * 64 + lane];
        }
        #pragma unroll
        for (int s = 0; s < 4; ++s) {
            // score = 0.5*||c||^2 - x.c ; rows are unit-norm so 0.5 is exact
            // to ~5e-7 (negligible vs THR margin).
            f32x4 acc = {0.5f, 0.5f, 0.5f, 0.5f};
            acc = __builtin_amdgcn_mfma_f32_16x16x32_bf16(ah[s][0], vh0, acc, 0, 0, 0);
            acc = __builtin_amdgcn_mfma_f32_16x16x32_bf16(al[s][0], vh0, acc, 0, 0, 0);
            acc = __builtin_amdgcn_mfma_f32_16x16x32_bf16(ah[s][0], vl0, acc, 0, 0, 0);
            acc = __builtin_amdgcn_mfma_f32_16x16x32_bf16(ah[s][1], vh1, acc, 0, 0, 0);
            acc = __builtin_amdgcn_mfma_f32_16x16x32_bf16(al[s][1], vh1, acc, 0, 0, 0);
            acc = __builtin_amdgcn_mfma_f32_16x16x32_bf16(ah[s][1], vl1, acc, 0, 0, 0);
            #pragma unroll
            for (int rr = 0; rr < 4; ++rr) {
                float d = acc[rr];
                int r = s * 4 + rr;
                bool take = d < d1[r];                    // strict: first min wins
                d2[r] = __builtin_amdgcn_fmed3f(d1[r], d2[r], d);  // min(d2,max(d1,d))
                d1[r] = fminf(d1[r], d);
                tb[r] = take ? t : tb[r];
            }
        }
    }

    // Butterfly + fused gather/store epilogue.
    const float4* cb4 = reinterpret_cast<const float4*>(cb);
    float4* oc4 = reinterpret_cast<float4*>(out_codes);
    #pragma unroll
    for (int r = 0; r < 16; ++r) {
        float dd1 = d1[r], dd2 = d2[r];
        int idv = tb[r] * 16 + c16;
        #pragma unroll
        for (int m = 1; m < 16; m <<= 1) {
            float d_o  = __shfl_xor(dd1, m, 64);
            int   i_o  = __shfl_xor(idv, m, 64);
            float d2_o = __shfl_xor(dd2, m, 64);
            float nd2 = fminf(fminf(dd2, d2_o), fmaxf(dd1, d_o));
            bool take = (d_o < dd1) || (d_o == dd1 && i_o < idv);
            dd1 = take ? d_o : dd1;
            idv = take ? i_o : idv;
            dd2 = nd2;
        }
        // idv/dd1/dd2 now uniform across the 16-lane group.
        int q = qb + (r >> 2) * 16 + kg * 4 + (r & 3);
        oc4[(size_t)q * 16 + c16] = cb4[(size_t)idv * 16 + c16];
        if (c16 == 0) {
            out_ids[q] = (float)idv;
            if (dd2 - dd1 < THR) {                       // near-tie -> rescan
                int slot = atomicAdd(counter, 1);
                worklist[slot] = q;
            }
        }
    }
}

// ---------------------------------------------------------------------------
// Fixup: one wave per worklist entry (grid-stride). Exact fp32 rescan,
// bitwise-identical math to the validated round-1 kernel; now also rewrites
// the code row for the flagged query.
// ---------------------------------------------------------------------------
__global__ __launch_bounds__(256) void vq_fixup(const float* __restrict__ codes,
                                                const float* __restrict__ cb,
                                                const float* __restrict__ hcsq,
                                                const int* __restrict__ worklist,
                                                const int* __restrict__ counter,
                                                float* __restrict__ out_codes,
                                                float* __restrict__ out_ids) {
    const int lane = threadIdx.x & 63;
    const int wid  = blockIdx.x * 4 + (threadIdx.x >> 6);
    const int nw   = gridDim.x * 4;
    const int cnt  = *counter;

    for (int w = wid; w < cnt; w += nw) {
        const int q = worklist[w];
        float x[64];
        const float4* xp = reinterpret_cast<const float4*>(codes + (size_t)q * DIM);
        #pragma unroll
        for (int i = 0; i < 16; ++i) {
            float4 v = xp[i];
            x[4*i+0] = v.x; x[4*i+1] = v.y; x[4*i+2] = v.z; x[4*i+3] = v.w;
        }
        float best = 3.4e38f; int bid = 0;
        for (int jj = 0; jj < 16; ++jj) {
            int k = jj * 64 + lane;
            const float4* cp = reinterpret_cast<const float4*>(cb + (size_t)k * DIM);
            float acc = hcsq[k];
            #pragma unroll
            for (int i = 0; i < 16; ++i) {
                float4 c = cp[i];
                acc = fmaf(-x[4*i+0], c.x, acc);
                acc = fmaf(-x[4*i+1], c.y, acc);
                acc = fmaf(-x[4*i+2], c.z, acc);
                acc = fmaf(-x[4*i+3], c.w, acc);
            }
            if (acc < best) { best = acc; bid = k; }   // strict: lowest k wins
        }
        #pragma unroll
        for (int m = 1; m < 64; m <<= 1) {
            float d_o = __shfl_xor(best, m, 64);
            int   i_o = __shfl_xor(bid, m, 64);
            bool take = (d_o < best) || (d_o == best && i_o < bid);
            best = take ? d_o : best;
            bid  = take ? i_o : bid;
        }
        int id = __shfl(bid, 0, 64);
        out_codes[(size_t)q * DIM + lane] = cb[(size_t)id * DIM + lane];
        if (lane == 0) out_ids[q] = (float)id;
    }
}

// ---------------------------------------------------------------------------
extern "C" void kernel_launch(void* const* d_in, const int* in_sizes, int n_in,
                              void* d_out, int out_size, void* d_ws, size_t ws_size,
                              hipStream_t stream) {
    const float* codes = (const float*)d_in[0];
    const float* cb    = (const float*)d_in[1];
    float* out         = (float*)d_out;

    float* out_codes = out;
    float* out_ids   = out + (size_t)M_TOTAL * DIM;

    // ws: [0,4K) hcsq | [4K,132K) bh | [132K,260K) bl | [264K) counter |
    //     [268K, 268K+1M) worklist
    float*  hcsq     = (float*)d_ws;
    short8* bh       = (short8*)((char*)d_ws + 4096);
    short8* bl       = (short8*)((char*)d_ws + 4096 + 128 * 1024);
    int*    counter  = (int*)((char*)d_ws + 264 * 1024);
    int*    worklist = (int*)((char*)d_ws + 268 * 1024);

    csq_kernel<<<NUM_NT, 64, 0, stream>>>(cb, hcsq, counter);
    cb_convert<<<32, 256, 0, stream>>>(cb, bh, bl);
    vq_approx<<<M_TOTAL / 256, 256, 0, stream>>>(codes, bh, bl, cb,
                                                 out_codes, out_ids,
                                                 worklist, counter);
    vq_fixup<<<512, 256, 0, stream>>>(codes, cb, hcsq, worklist, counter,
                                      out_codes, out_ids);
}

// Round 16
// 154.150 us; speedup vs baseline: 1.1151x; 1.0021x over previous
//
#include <hip/hip_runtime.h>

// VQ nearest-neighbor: codes (64,4096,64) fp32, codebook (1024,64) fp32.
// Outputs flat in d_out: quant_codes [M*64] f32, then quant_id [M] (as f32).
//
// Round 16 = round 15 VERBATIM (verified, 154.5us) with ONE change:
// per-wave tile-phase rotation. Co-resident waves start the codebook sweep
// at different tiles (phase = (global_wave & 3) * 16, wrap mod 64), so one
// wave's MFMA burst overlaps another's tracking-VALU phase instead of
// colliding (lockstep anti-correlation). Order-dependence of the first-min
// tie-break is safe: exact ties have gap 0 < THR -> flagged -> exact fixup
// resolves with canonical lowest-index semantics.

#define NUM_NT 1024
#define DIM 64
#define M_TOTAL (64 * 4096)
#define NTILES 64
#define THR 1.0e-3f            // verified r13/r15 (5x margin over ~2e-4 bound)

typedef __attribute__((ext_vector_type(8))) short short8;   // 8 bf16
typedef __attribute__((ext_vector_type(4))) float f32x4;

static __device__ __forceinline__ unsigned short f2bf_rne(float f) {
    unsigned u = __builtin_bit_cast(unsigned, f);
    u += 0x7FFFu + ((u >> 16) & 1u);          // round-to-nearest-even
    return (unsigned short)(u >> 16);
}
static __device__ __forceinline__ float bf2f(unsigned short h) {
    unsigned u = ((unsigned)h) << 16;
    return __builtin_bit_cast(float, u);
}

// ---------------------------------------------------------------------------
// Phase 0a: hcsq[k] = 0.5*||c_k||^2 (fixup's r1-exact math needs it);
// block 0 zeroes the worklist counter. (r15-verbatim)
// ---------------------------------------------------------------------------
__global__ __launch_bounds__(64) void csq_kernel(const float* __restrict__ cb,
                                                 float* __restrict__ hcsq,
                                                 int* __restrict__ counter) {
    int k = blockIdx.x, d = threadIdx.x;
    if (k == 0 && d == 0) *counter = 0;
    float v = cb[k * DIM + d];
    float s = v * v;
    #pragma unroll
    for (int off = 32; off > 0; off >>= 1) s += __shfl_down(s, off);
    if (d == 0) hcsq[k] = 0.5f * s;
}

// ---------------------------------------------------------------------------
// Phase 0b: codebook -> bf16 hi/lo fragments in MFMA B-layout. (r15-verbatim)
// ---------------------------------------------------------------------------
__global__ __launch_bounds__(256) void cb_convert(const float* __restrict__ cb,
                                                  short8* __restrict__ bh,
                                                  short8* __restrict__ bl) {
    int gtid = blockIdx.x * 256 + threadIdx.x;   // 8192 = 128 frags x 64 lanes
    int f = gtid >> 6;
    int lane = gtid & 63;
    int t = f >> 1, kk = f & 1;
    int n = t * 16 + (lane & 15);
    int k0 = kk * 32 + 8 * (lane >> 4);
    const float* p = cb + n * DIM + k0;
    short8 h, l;
    #pragma unroll
    for (int e = 0; e < 8; ++e) {
        float v = p[e];
        unsigned short hb = f2bf_rne(v);
        h[e] = (short)hb;
        l[e] = (short)f2bf_rne(v - bf2f(hb));
    }
    bh[f * 64 + lane] = h;
    bl[f * 64 + lane] = l;
}

// ---------------------------------------------------------------------------
// Phase 1: approx scores via 3-pass bf16 MFMA, 64 queries/wave, register
// double-buffer B prefetch, fmed3 second-best, fused gather/store epilogue
// (r15-verbatim) + per-wave tile-phase rotation (NEW).
// ---------------------------------------------------------------------------
__global__ __launch_bounds__(256, 2) void vq_approx(const float* __restrict__ codes,
                                                    const short8* __restrict__ bh,
                                                    const short8* __restrict__ bl,
                                                    const float* __restrict__ cb,
                                                    float* __restrict__ out_codes,
                                                    float* __restrict__ out_ids,
                                                    int* __restrict__ worklist,
                                                    int* __restrict__ counter) {
    const int lane = threadIdx.x & 63;
    const int wv   = threadIdx.x >> 6;
    const int gw   = blockIdx.x * 4 + wv;          // global wave id
    const int qb   = gw * 64;                      // 64 queries per wave
    const int c16  = lane & 15;
    const int kg   = lane >> 4;
    const int phase = (gw & 3) * 16;               // tile-phase rotation

    short8 ah[4][2], al[4][2];
    #pragma unroll
    for (int s = 0; s < 4; ++s) {
        const float* xr = codes + (size_t)(qb + s * 16 + c16) * DIM + kg * 8;
        #pragma unroll
        for (int e = 0; e < 8; ++e) {
            float v = -xr[e];
            unsigned short hb = f2bf_rne(v);
            ah[s][0][e] = (short)hb;
            al[s][0][e] = (short)f2bf_rne(v - bf2f(hb));
            float w = -xr[32 + e];
            unsigned short hw = f2bf_rne(w);
            ah[s][1][e] = (short)hw;
            al[s][1][e] = (short)f2bf_rne(w - bf2f(hw));
        }
    }

    float d1[16], d2[16];
    int   tb[16];
    #pragma unroll
    for (int r = 0; r < 16; ++r) { d1[r] = 3.4e38f; d2[r] = 3.4e38f; tb[r] = 0; }

    short8 pvh0 = bh[(phase * 2 + 0) * 64 + lane];
    short8 pvl0 = bl[(phase * 2 + 0) * 64 + lane];
    short8 pvh1 = bh[(phase * 2 + 1) * 64 + lane];
    short8 pvl1 = bl[(phase * 2 + 1) * 64 + lane];

    for (int tt = 0; tt < NTILES; ++tt) {
        const int t = (tt + phase) & (NTILES - 1);   // rotated tile index
        short8 vh0 = pvh0, vl0 = pvl0, vh1 = pvh1, vl1 = pvl1;
        if (tt + 1 < NTILES) {            // issue next-tile loads before MFMA
            const int tn = (tt + 1 + phase) & (NTILES - 1);
            pvh0 = bh[(tn * 2 + 0) * 64 + lane];
            pvl0 = bl[(tn * 2 + 0) * 64 + lane];
            pvh1 = bh[(tn * 2 + 1) * 64 + lane];
            pvl1 = bl[(tn * 2 + 1) * 64 + lane];
        }
        #pragma unroll
        for (int s = 0; s < 4; ++s) {
            // score = 0.5*||c||^2 - x.c ; rows unit-norm so 0.5 exact ~5e-7
            f32x4 acc = {0.5f, 0.5f, 0.5f, 0.5f};
            acc = __builtin_amdgcn_mfma_f32_16x16x32_bf16(ah[s][0], vh0, acc, 0, 0, 0);
            acc = __builtin_amdgcn_mfma_f32_16x16x32_bf16(al[s][0], vh0, acc, 0, 0, 0);
            acc = __builtin_amdgcn_mfma_f32_16x16x32_bf16(ah[s][0], vl0, acc, 0, 0, 0);
            acc = __builtin_amdgcn_mfma_f32_16x16x32_bf16(ah[s][1], vh1, acc, 0, 0, 0);
            acc = __builtin_amdgcn_mfma_f32_16x16x32_bf16(al[s][1], vh1, acc, 0, 0, 0);
            acc = __builtin_amdgcn_mfma_f32_16x16x32_bf16(ah[s][1], vl1, acc, 0, 0, 0);
            #pragma unroll
            for (int rr = 0; rr < 4; ++rr) {
                float d = acc[rr];
                int r = s * 4 + rr;
                bool take = d < d1[r];                    // first min (ties flagged)
                d2[r] = __builtin_amdgcn_fmed3f(d1[r], d2[r], d);  // min(d2,max(d1,d))
                d1[r] = fminf(d1[r], d);
                tb[r] = take ? t : tb[r];
            }
        }
    }

    // Butterfly + fused gather/store epilogue. (r15-verbatim)
    const float4* cb4 = reinterpret_cast<const float4*>(cb);
    float4* oc4 = reinterpret_cast<float4*>(out_codes);
    #pragma unroll
    for (int r = 0; r < 16; ++r) {
        float dd1 = d1[r], dd2 = d2[r];
        int idv = tb[r] * 16 + c16;
        #pragma unroll
        for (int m = 1; m < 16; m <<= 1) {
            float d_o  = __shfl_xor(dd1, m, 64);
            int   i_o  = __shfl_xor(idv, m, 64);
            float d2_o = __shfl_xor(dd2, m, 64);
            float nd2 = fminf(fminf(dd2, d2_o), fmaxf(dd1, d_o));
            bool take = (d_o < dd1) || (d_o == dd1 && i_o < idv);
            dd1 = take ? d_o : dd1;
            idv = take ? i_o : idv;
            dd2 = nd2;
        }
        int q = qb + (r >> 2) * 16 + kg * 4 + (r & 3);
        oc4[(size_t)q * 16 + c16] = cb4[(size_t)idv * 16 + c16];
        if (c16 == 0) {
            out_ids[q] = (float)idv;
            if (dd2 - dd1 < THR) {                       // near-tie -> rescan
                int slot = atomicAdd(counter, 1);
                worklist[slot] = q;
            }
        }
    }
}

// ---------------------------------------------------------------------------
// Fixup: one wave per worklist entry (grid-stride). Exact fp32 rescan,
// bitwise-identical math to the validated round-1 kernel; rewrites the
// code row for flagged queries. (r15-verbatim)
// ---------------------------------------------------------------------------
__global__ __launch_bounds__(256) void vq_fixup(const float* __restrict__ codes,
                                                const float* __restrict__ cb,
                                                const float* __restrict__ hcsq,
                                                const int* __restrict__ worklist,
                                                const int* __restrict__ counter,
                                                float* __restrict__ out_codes,
                                                float* __restrict__ out_ids) {
    const int lane = threadIdx.x & 63;
    const int wid  = blockIdx.x * 4 + (threadIdx.x >> 6);
    const int nw   = gridDim.x * 4;
    const int cnt  = *counter;

    for (int w = wid; w < cnt; w += nw) {
        const int q = worklist[w];
        float x[64];
        const float4* xp = reinterpret_cast<const float4*>(codes + (size_t)q * DIM);
        #pragma unroll
        for (int i = 0; i < 16; ++i) {
            float4 v = xp[i];
            x[4*i+0] = v.x; x[4*i+1] = v.y; x[4*i+2] = v.z; x[4*i+3] = v.w;
        }
        float best = 3.4e38f; int bid = 0;
        for (int jj = 0; jj < 16; ++jj) {
            int k = jj * 64 + lane;
            const float4* cp = reinterpret_cast<const float4*>(cb + (size_t)k * DIM);
            float acc = hcsq[k];
            #pragma unroll
            for (int i = 0; i < 16; ++i) {
                float4 c = cp[i];
                acc = fmaf(-x[4*i+0], c.x, acc);
                acc = fmaf(-x[4*i+1], c.y, acc);
                acc = fmaf(-x[4*i+2], c.z, acc);
                acc = fmaf(-x[4*i+3], c.w, acc);
            }
            if (acc < best) { best = acc; bid = k; }   // strict: lowest k wins
        }
        #pragma unroll
        for (int m = 1; m < 64; m <<= 1) {
            float d_o = __shfl_xor(best, m, 64);
            int   i_o = __shfl_xor(bid, m, 64);
            bool take = (d_o < best) || (d_o == best && i_o < bid);
            best = take ? d_o : best;
            bid  = take ? i_o : bid;
        }
        int id = __shfl(bid, 0, 64);
        out_codes[(size_t)q * DIM + lane] = cb[(size_t)id * DIM + lane];
        if (lane == 0) out_ids[q] = (float)id;
    }
}

// ---------------------------------------------------------------------------
extern "C" void kernel_launch(void* const* d_in, const int* in_sizes, int n_in,
                              void* d_out, int out_size, void* d_ws, size_t ws_size,
                              hipStream_t stream) {
    const float* codes = (const float*)d_in[0];
    const float* cb    = (const float*)d_in[1];
    float* out         = (float*)d_out;

    float* out_codes = out;
    float* out_ids   = out + (size_t)M_TOTAL * DIM;

    // ws: [0,4K) hcsq | [4K,132K) bh | [132K,260K) bl | [264K) counter |
    //     [268K, 268K+1M) worklist
    float*  hcsq     = (float*)d_ws;
    short8* bh       = (short8*)((char*)d_ws + 4096);
    short8* bl       = (short8*)((char*)d_ws + 4096 + 128 * 1024);
    int*    counter  = (int*)((char*)d_ws + 264 * 1024);
    int*    worklist = (int*)((char*)d_ws + 268 * 1024);

    csq_kernel<<<NUM_NT, 64, 0, stream>>>(cb, hcsq, counter);
    cb_convert<<<32, 256, 0, stream>>>(cb, bh, bl);
    vq_approx<<<M_TOTAL / 256, 256, 0, stream>>>(codes, bh, bl, cb,
                                                 out_codes, out_ids,
                                                 worklist, counter);
    vq_fixup<<<512, 256, 0, stream>>>(codes, cb, hcsq, worklist, counter,
                                      out_codes, out_ids);
}